// Round 5
// baseline (333.524 us; speedup 1.0000x reference)
//
#include <hip/hip_runtime.h>

// B=32, L=T=S=128, D=512, M = B*L = 4096.
#define DD 512
#define SS 128
#define TT4 4          // t-rows per attn block
#define SCH16 16       // s-chunk rows staged in LDS
#define RW 520         // LDS row width in shorts (16B-aligned, padded)
#define C2F 2.8853900817779268f   // 2*log2(e)
#define L2EF 1.4426950408889634f

typedef __bf16 bf16x8 __attribute__((ext_vector_type(8)));
typedef float f32x4 __attribute__((ext_vector_type(4)));
typedef unsigned int uint32x4 __attribute__((ext_vector_type(4)));

__device__ __forceinline__ unsigned short f2bf(float f) {
    unsigned int u = __builtin_bit_cast(unsigned int, f);
    u += 0x7fffu + ((u >> 16) & 1u);            // RTNE
    return (unsigned short)(u >> 16);
}
__device__ __forceinline__ float bflo(unsigned int u) { return __builtin_bit_cast(float, u << 16); }
__device__ __forceinline__ float bfhi(unsigned int u) { return __builtin_bit_cast(float, u & 0xffff0000u); }

// ---------------------------------------------------------------------------
// f32 -> bf16 elementwise (n8 = n/8 vector groups)
// ---------------------------------------------------------------------------
__global__ __launch_bounds__(256)
void f32_to_bf16_k(const float* __restrict__ in, unsigned short* __restrict__ out, int n8)
{
    int i = blockIdx.x * 256 + threadIdx.x;
    if (i < n8) {
        const float4 a = ((const float4*)in)[2 * i];
        const float4 b = ((const float4*)in)[2 * i + 1];
        uint32x4 o;
        o[0] = (unsigned)f2bf(a.x) | ((unsigned)f2bf(a.y) << 16);
        o[1] = (unsigned)f2bf(a.z) | ((unsigned)f2bf(a.w) << 16);
        o[2] = (unsigned)f2bf(b.x) | ((unsigned)f2bf(b.y) << 16);
        o[3] = (unsigned)f2bf(b.z) | ((unsigned)f2bf(b.w) << 16);
        ((uint32x4*)out)[i] = o;
    }
}

// ---------------------------------------------------------------------------
// Transpose + convert: out[c][r] = bf16(in[r][c]); grid (C/64, R/64).
// ---------------------------------------------------------------------------
__global__ __launch_bounds__(256)
void transpose_bf16(const float* __restrict__ in, unsigned short* __restrict__ out, int R, int C)
{
    __shared__ float t[64][65];
    const int r0 = blockIdx.y * 64, c0 = blockIdx.x * 64;
    const int tid = threadIdx.x;
    const int lc = tid & 63, lr = tid >> 6;
    #pragma unroll
    for (int i = 0; i < 16; ++i) {
        int r = lr + i * 4;
        t[r][lc] = in[(size_t)(r0 + r) * C + c0 + lc];
    }
    __syncthreads();
    #pragma unroll
    for (int i = 0; i < 16; ++i) {
        int rr = lr + i * 4;
        out[(size_t)(c0 + rr) * R + r0 + lc] = f2bf(t[lc][rr]);
    }
}

// ---------------------------------------------------------------------------
// Projection GEMM (fused Wq|Wc): X[4096,512]bf16 @ Bt[1024,512]^T.
// cols 0..511  -> outW = (X@Wq + bq)*C2   (bf16)
// cols 512..1023 -> outU = X@Wc           (bf16)
// 64x64 tile, BK=64, 256 thr (4 waves 2x2), reg-prefetch. Grid (16, 64).
// ---------------------------------------------------------------------------
__global__ __launch_bounds__(256)
void gemm_proj(const unsigned short* __restrict__ A,
               const unsigned short* __restrict__ Bt,
               const float* __restrict__ bq,
               unsigned short* __restrict__ outW,
               unsigned short* __restrict__ outU)
{
    constexpr int K = 512, LDA = 72;
    __shared__ __align__(16) unsigned short As[64][LDA];
    __shared__ __align__(16) unsigned short Bs[64][LDA];

    const int tid = threadIdx.x;
    const int n0 = blockIdx.x * 64, m0 = blockIdx.y * 64;
    const int lane = tid & 63, wid = tid >> 6;
    const int wr = wid >> 1, wc = wid & 1;
    const int lr = lane & 15, kb = lane >> 4;

    f32x4 acc[2][2] = {};
    uint32x4 ra[2], rb[2];

    auto LOADK = [&](int k0) {
        #pragma unroll
        for (int j = 0; j < 2; ++j) {
            int id = tid + 256 * j; int r = id >> 3, s = id & 7;
            ra[j] = *(const uint32x4*)&A[(size_t)(m0 + r) * K + k0 + s * 8];
            rb[j] = *(const uint32x4*)&Bt[(size_t)(n0 + r) * K + k0 + s * 8];
        }
    };

    LOADK(0);
    #pragma unroll 1
    for (int step = 0; step < K / 64; ++step) {
        __syncthreads();
        #pragma unroll
        for (int j = 0; j < 2; ++j) {
            int id = tid + 256 * j; int r = id >> 3, s = id & 7;
            *(uint32x4*)&As[r][s * 8] = ra[j];
            *(uint32x4*)&Bs[r][s * 8] = rb[j];
        }
        __syncthreads();
        if (step + 1 < K / 64) LOADK((step + 1) * 64);
        #pragma unroll
        for (int kk = 0; kk < 64; kk += 32) {
            bf16x8 b0 = __builtin_bit_cast(bf16x8, *(const uint32x4*)&Bs[wc * 32 + lr][kk + kb * 8]);
            bf16x8 b1 = __builtin_bit_cast(bf16x8, *(const uint32x4*)&Bs[wc * 32 + 16 + lr][kk + kb * 8]);
            #pragma unroll
            for (int mf = 0; mf < 2; ++mf) {
                bf16x8 a0 = __builtin_bit_cast(bf16x8, *(const uint32x4*)&As[wr * 32 + mf * 16 + lr][kk + kb * 8]);
                acc[mf][0] = __builtin_amdgcn_mfma_f32_16x16x32_bf16(a0, b0, acc[mf][0], 0, 0, 0);
                acc[mf][1] = __builtin_amdgcn_mfma_f32_16x16x32_bf16(a0, b1, acc[mf][1], 0, 0, 0);
            }
        }
    }

    #pragma unroll
    for (int nf = 0; nf < 2; ++nf) {
        const int col = n0 + wc * 32 + nf * 16 + lr;
        #pragma unroll
        for (int mf = 0; mf < 2; ++mf) {
            const int row = m0 + wr * 32 + mf * 16 + kb * 4;
            #pragma unroll
            for (int r = 0; r < 4; ++r) {
                const float valf = acc[mf][nf][r];
                if (col < 512) outW[(size_t)(row + r) * 512 + col] = f2bf((valf + bq[col]) * C2F);
                else           outU[(size_t)(row + r) * 512 + (col - 512)] = f2bf(valf);
            }
        }
    }
}

// ---------------------------------------------------------------------------
// Final GEMM with fused mix+concat A-operand:
// A[m][k] = k<512 ? om*c1[m][k]+m*c2[m][k] (bf16) : om*no[m][k-512]+m*cs[m][k-512] (f32)
// C[4096,512] f32 = A @ Woutt[512,1024]^T + bout. Grid (8, 64).
// ---------------------------------------------------------------------------
__global__ __launch_bounds__(256)
void gemm_final(const unsigned short* __restrict__ c1, const unsigned short* __restrict__ c2,
                const float* __restrict__ no, const float* __restrict__ cs,
                const float* __restrict__ mix,
                const unsigned short* __restrict__ Bt,   // [512][1024]
                const float* __restrict__ bout, float* __restrict__ out)
{
    constexpr int K = 1024, LDA = 72;
    __shared__ __align__(16) unsigned short As[64][LDA];
    __shared__ __align__(16) unsigned short Bs[64][LDA];

    const int tid = threadIdx.x;
    const int n0 = blockIdx.x * 64, m0 = blockIdx.y * 64;
    const int lane = tid & 63, wid = tid >> 6;
    const int wr = wid >> 1, wc = wid & 1;
    const int lr = lane & 15, kb = lane >> 4;
    const float mxv = mix[0], omv = 1.0f - mxv;

    f32x4 acc[2][2] = {};
    uint32x4 ra[2], rb[2];

    auto LOADK = [&](int k0) {
        #pragma unroll
        for (int j = 0; j < 2; ++j) {
            int id = tid + 256 * j; int r = id >> 3, s = id & 7;
            const size_t row = m0 + r;
            const int k = k0 + s * 8;
            uint32x4 o;
            if (k < 512) {
                const uint32x4 x1 = *(const uint32x4*)&c1[row * 512 + k];
                const uint32x4 x2 = *(const uint32x4*)&c2[row * 512 + k];
                #pragma unroll
                for (int q = 0; q < 4; ++q) {
                    float lo = omv * bflo(x1[q]) + mxv * bflo(x2[q]);
                    float hi = omv * bfhi(x1[q]) + mxv * bfhi(x2[q]);
                    o[q] = (unsigned)f2bf(lo) | ((unsigned)f2bf(hi) << 16);
                }
            } else {
                const float* n1 = &no[row * 512 + k - 512];
                const float* s1 = &cs[row * 512 + k - 512];
                const float4 a1 = *(const float4*)n1, a2 = *(const float4*)(n1 + 4);
                const float4 b1 = *(const float4*)s1, b2 = *(const float4*)(s1 + 4);
                o[0] = (unsigned)f2bf(omv * a1.x + mxv * b1.x) | ((unsigned)f2bf(omv * a1.y + mxv * b1.y) << 16);
                o[1] = (unsigned)f2bf(omv * a1.z + mxv * b1.z) | ((unsigned)f2bf(omv * a1.w + mxv * b1.w) << 16);
                o[2] = (unsigned)f2bf(omv * a2.x + mxv * b2.x) | ((unsigned)f2bf(omv * a2.y + mxv * b2.y) << 16);
                o[3] = (unsigned)f2bf(omv * a2.z + mxv * b2.z) | ((unsigned)f2bf(omv * a2.w + mxv * b2.w) << 16);
            }
            ra[j] = o;
            rb[j] = *(const uint32x4*)&Bt[(size_t)(n0 + r) * K + k0 + s * 8];
        }
    };

    LOADK(0);
    #pragma unroll 1
    for (int step = 0; step < K / 64; ++step) {
        __syncthreads();
        #pragma unroll
        for (int j = 0; j < 2; ++j) {
            int id = tid + 256 * j; int r = id >> 3, s = id & 7;
            *(uint32x4*)&As[r][s * 8] = ra[j];
            *(uint32x4*)&Bs[r][s * 8] = rb[j];
        }
        __syncthreads();
        if (step + 1 < K / 64) LOADK((step + 1) * 64);
        #pragma unroll
        for (int kk = 0; kk < 64; kk += 32) {
            bf16x8 b0 = __builtin_bit_cast(bf16x8, *(const uint32x4*)&Bs[wc * 32 + lr][kk + kb * 8]);
            bf16x8 b1 = __builtin_bit_cast(bf16x8, *(const uint32x4*)&Bs[wc * 32 + 16 + lr][kk + kb * 8]);
            #pragma unroll
            for (int mf = 0; mf < 2; ++mf) {
                bf16x8 a0 = __builtin_bit_cast(bf16x8, *(const uint32x4*)&As[wr * 32 + mf * 16 + lr][kk + kb * 8]);
                acc[mf][0] = __builtin_amdgcn_mfma_f32_16x16x32_bf16(a0, b0, acc[mf][0], 0, 0, 0);
                acc[mf][1] = __builtin_amdgcn_mfma_f32_16x16x32_bf16(a0, b1, acc[mf][1], 0, 0, 0);
            }
        }
    }

    #pragma unroll
    for (int nf = 0; nf < 2; ++nf) {
        const int col = n0 + wc * 32 + nf * 16 + lr;
        const float bv = bout[col];
        #pragma unroll
        for (int mf = 0; mf < 2; ++mf) {
            const int row = m0 + wr * 32 + mf * 16 + kb * 4;
            #pragma unroll
            for (int r = 0; r < 4; ++r)
                out[(size_t)(row + r) * 512 + col] = acc[mf][nf][r] + bv;
        }
    }
}

// ---------------------------------------------------------------------------
// Fused scores + softmax + context. Block = (b, 4 t-rows), 512 thr, ~25KB LDS,
// grid 1024 blocks -> 4 blocks/CU.
// Phase A: thread = (t, s, d-oct of 64): score partial, shfl-reduce over oct.
//   LDS tiles stored with bit-swapped 16B-group index P=((G&7)<<3)|(G>>3) so
//   the 8 concurrent octs read consecutive 16B groups (conflict-free).
// Phase B: mem (bf16) staged per s-chunk in LDS; wave = (t, d-half).
// ---------------------------------------------------------------------------
__global__ __launch_bounds__(512, 8)
void attn_fused(const unsigned short* __restrict__ wq,  // [B,T,D] bf16, (.+bq)*C2
                const unsigned short* __restrict__ uh,  // [B,S,D] bf16
                const float* __restrict__ v,            // [D] f32
                const unsigned short* __restrict__ mem, // [B,S,D] bf16
                unsigned short* __restrict__ c_out)     // [B,T,D] bf16
{
    __shared__ __align__(16) unsigned short s_wq[TT4 * RW];
    __shared__ __align__(16) unsigned short s_uh[SCH16 * RW];
    __shared__ __align__(16) float s_v2[DD];
    __shared__ float s_sc[TT4 * SS];

    const int b = blockIdx.y, t0 = blockIdx.x * TT4;
    const int tid = threadIdx.x;

    // ---- stage wq tile (swizzled) + v2 (swizzled) ----
    if (tid < 256) {
        const int row = tid >> 6, G = tid & 63;
        const int P = ((G & 7) << 3) | (G >> 3);
        *(uint32x4*)&s_wq[row * RW + P * 8] =
            *(const uint32x4*)&wq[((size_t)b * SS + t0 + row) * DD + G * 8];
    } else if (tid < 384) {
        const int H = tid - 256;                       // 0..127
        const int P = ((H & 15) << 3) | (H >> 4);
        float4 val = *(const float4*)&v[H * 4];
        val.x *= 2.f; val.y *= 2.f; val.z *= 2.f; val.w *= 2.f;
        *(float4*)&s_v2[P * 4] = val;
    }

    const int oct = tid & 7;            // d-oct: 64 elems at logical oct*64
    const int sr  = (tid >> 3) & 15;    // s within chunk
    const int t   = tid >> 7;           // 0..3

    // ---- phase A: scores ----
    for (int sc0 = 0; sc0 < SS; sc0 += SCH16) {
        __syncthreads();                // staging visible / prev chunk consumed
        {
            int i = tid;
            #pragma unroll
            for (int rep = 0; rep < 2; ++rep, i += 512) {
                const int row = i >> 6, G = i & 63;
                const int P = ((G & 7) << 3) | (G >> 3);
                *(uint32x4*)&s_uh[row * RW + P * 8] =
                    *(const uint32x4*)&uh[((size_t)b * SS + sc0 + row) * DD + G * 8];
            }
        }
        __syncthreads();

        const unsigned short* wrow = &s_wq[t * RW];
        const unsigned short* urow = &s_uh[sr * RW];

        float a0 = 0.f, a1 = 0.f, a2 = 0.f, a3 = 0.f;
        #pragma unroll 4
        for (int j = 0; j < 8; ++j) {
            const uint32x4 w4 = *(const uint32x4*)&wrow[(8 * j + oct) * 8];
            const uint32x4 u4 = *(const uint32x4*)&urow[(8 * j + oct) * 8];
            const float4 vA = *(const float4*)&s_v2[(16 * j + oct) * 4];
            const float4 vB = *(const float4*)&s_v2[(16 * j + 8 + oct) * 4];
            float x, e;
            x = fmaf(C2F, bflo(u4[0]), bflo(w4[0])); e = __builtin_amdgcn_exp2f(x);
            a0 = fmaf(vA.x, __builtin_amdgcn_rcpf(e + 1.f), a0);
            x = fmaf(C2F, bfhi(u4[0]), bfhi(w4[0])); e = __builtin_amdgcn_exp2f(x);
            a1 = fmaf(vA.y, __builtin_amdgcn_rcpf(e + 1.f), a1);
            x = fmaf(C2F, bflo(u4[1]), bflo(w4[1])); e = __builtin_amdgcn_exp2f(x);
            a2 = fmaf(vA.z, __builtin_amdgcn_rcpf(e + 1.f), a2);
            x = fmaf(C2F, bfhi(u4[1]), bfhi(w4[1])); e = __builtin_amdgcn_exp2f(x);
            a3 = fmaf(vA.w, __builtin_amdgcn_rcpf(e + 1.f), a3);
            x = fmaf(C2F, bflo(u4[2]), bflo(w4[2])); e = __builtin_amdgcn_exp2f(x);
            a0 = fmaf(vB.x, __builtin_amdgcn_rcpf(e + 1.f), a0);
            x = fmaf(C2F, bfhi(u4[2]), bfhi(w4[2])); e = __builtin_amdgcn_exp2f(x);
            a1 = fmaf(vB.y, __builtin_amdgcn_rcpf(e + 1.f), a1);
            x = fmaf(C2F, bflo(u4[3]), bflo(w4[3])); e = __builtin_amdgcn_exp2f(x);
            a2 = fmaf(vB.z, __builtin_amdgcn_rcpf(e + 1.f), a2);
            x = fmaf(C2F, bfhi(u4[3]), bfhi(w4[3])); e = __builtin_amdgcn_exp2f(x);
            a3 = fmaf(vB.w, __builtin_amdgcn_rcpf(e + 1.f), a3);
        }
        float p = (a0 + a1) + (a2 + a3);
        p += __shfl_xor(p, 1);
        p += __shfl_xor(p, 2);
        p += __shfl_xor(p, 4);
        if (oct == 0) s_sc[t * SS + sc0 + sr] = -p;
    }
    __syncthreads();

    // ---- softmax: 4 rows x 128, threads 0..127 ----
    if (tid < 128) {
        const int tr = tid >> 5, l32 = tid & 31;
        float x0 = s_sc[tr * SS + l32];
        float x1 = s_sc[tr * SS + l32 + 32];
        float x2 = s_sc[tr * SS + l32 + 64];
        float x3 = s_sc[tr * SS + l32 + 96];
        float mx = fmaxf(fmaxf(x0, x1), fmaxf(x2, x3));
        #pragma unroll
        for (int off = 16; off > 0; off >>= 1) mx = fmaxf(mx, __shfl_xor(mx, off));
        const float e0 = __builtin_amdgcn_exp2f((x0 - mx) * L2EF);
        const float e1 = __builtin_amdgcn_exp2f((x1 - mx) * L2EF);
        const float e2 = __builtin_amdgcn_exp2f((x2 - mx) * L2EF);
        const float e3 = __builtin_amdgcn_exp2f((x3 - mx) * L2EF);
        float sum = (e0 + e1) + (e2 + e3);
        #pragma unroll
        for (int off = 16; off > 0; off >>= 1) sum += __shfl_xor(sum, off);
        const float rs = __builtin_amdgcn_rcpf(sum);
        s_sc[tr * SS + l32]      = e0 * rs;
        s_sc[tr * SS + l32 + 32] = e1 * rs;
        s_sc[tr * SS + l32 + 64] = e2 * rs;
        s_sc[tr * SS + l32 + 96] = e3 * rs;
    }

    // ---- phase B: context from LDS-staged mem chunks ----
    const int w = tid >> 6, lane = tid & 63;
    const int tb = w & 3, half = w >> 2;
    const int d = half * 256 + lane * 4;
    f32x4 ac = {0.f, 0.f, 0.f, 0.f};

    for (int sc0 = 0; sc0 < SS; sc0 += SCH16) {
        __syncthreads();                // softmax done / prev chunk consumed
        {
            int i = tid;
            #pragma unroll
            for (int rep = 0; rep < 2; ++rep, i += 512) {
                const int row = i >> 6, G = i & 63;
                *(uint32x4*)&s_uh[row * RW + G * 8] =        // linear layout
                    *(const uint32x4*)&mem[((size_t)b * SS + sc0 + row) * DD + G * 8];
            }
        }
        __syncthreads();
        #pragma unroll
        for (int srow = 0; srow < SCH16; ++srow) {
            const float e = s_sc[tb * SS + sc0 + srow];
            const uint2 mv = *(const uint2*)&s_uh[srow * RW + d];
            ac[0] = fmaf(e, bflo(mv.x), ac[0]);
            ac[1] = fmaf(e, bfhi(mv.x), ac[1]);
            ac[2] = fmaf(e, bflo(mv.y), ac[2]);
            ac[3] = fmaf(e, bfhi(mv.y), ac[3]);
        }
    }
    uint2 st;
    st.x = (unsigned)f2bf(ac[0]) | ((unsigned)f2bf(ac[1]) << 16);
    st.y = (unsigned)f2bf(ac[2]) | ((unsigned)f2bf(ac[3]) << 16);
    *(uint2*)&c_out[((size_t)b * SS + t0 + tb) * DD + d] = st;
}

// ---------------------------------------------------------------------------
extern "C" void kernel_launch(void* const* d_in, const int* in_sizes, int n_in,
                              void* d_out, int out_size, void* d_ws, size_t ws_size,
                              hipStream_t stream) {
    const float* cs   = (const float*)d_in[0];
    const float* no   = (const float*)d_in[1];
    const float* Wq   = (const float*)d_in[2];
    const float* bq   = (const float*)d_in[3];
    const float* Wc   = (const float*)d_in[4];
    const float* v    = (const float*)d_in[5];
    const float* Wout = (const float*)d_in[6];
    const float* bout = (const float*)d_in[7];
    const float* mix  = (const float*)d_in[8];
    float* out = (float*)d_out;

    typedef unsigned short us;
    char* ws = (char*)d_ws;
    us* cs_bf = (us*)(ws);                     //  0..4 MB
    us* no_bf = (us*)(ws + (4u  << 20));       //  4..8 MB
    us* Wqct  = (us*)(ws + (8u  << 20));       //  8..9 MB   [1024][512] = Wq^T | Wc^T
    us* Woutt = (us*)(ws + (9u  << 20));       //  9..10 MB  [512][1024]
    us* wq1   = (us*)(ws + (10u << 20));       // 10..14 MB
    us* uh2   = (us*)(ws + (14u << 20));       // 14..18 MB
    us* wq2   = (us*)(ws + (18u << 20));       // 18..22 MB
    us* uh1   = (us*)(ws + (22u << 20));       // 22..26 MB
    us* c1    = (us*)(ws + (26u << 20));       // 26..30 MB
    us* c2    = (us*)(ws + (10u << 20));       // overlays wq1 (dead after attn1)

    const dim3 b256(256);
    const int n8 = 4096 * DD / 8;              // 262144

    f32_to_bf16_k<<<dim3(n8 / 256), b256, 0, stream>>>(cs, cs_bf, n8);
    f32_to_bf16_k<<<dim3(n8 / 256), b256, 0, stream>>>(no, no_bf, n8);
    transpose_bf16<<<dim3(8, 8),  b256, 0, stream>>>(Wq, Wqct, 512, 512);
    transpose_bf16<<<dim3(8, 8),  b256, 0, stream>>>(Wc, Wqct + 512 * 512, 512, 512);
    transpose_bf16<<<dim3(8, 16), b256, 0, stream>>>(Wout, Woutt, 1024, 512);

    // proj: X@[Wq|Wc]  (A=no -> wq1, uh2 ; A=cs -> wq2, uh1)
    gemm_proj<<<dim3(16, 64), b256, 0, stream>>>(no_bf, Wqct, bq, wq1, uh2);
    gemm_proj<<<dim3(16, 64), b256, 0, stream>>>(cs_bf, Wqct, bq, wq2, uh1);

    // attn: dir1 (source=no, memory=cs), dir2 (source=cs, memory=no)
    attn_fused<<<dim3(32, 32), dim3(512), 0, stream>>>(wq1, uh1, v, cs_bf, c1);
    attn_fused<<<dim3(32, 32), dim3(512), 0, stream>>>(wq2, uh2, v, no_bf, c2);

    // final: [mix(c1,c2) | mix(no,cs)] @ Wout + bout
    gemm_final<<<dim3(8, 64), b256, 0, stream>>>(c1, c2, no, cs, mix, Woutt, bout, out);
}